// Round 6
// baseline (240.085 us; speedup 1.0000x reference)
//
#include <hip/hip_runtime.h>

// ---------------------------------------------------------------------------
// MHA: out = softmax_causal((xWq)(xWk)^T / sqrt(64)) (xWv) Wo
// B=4 T=2048 D=1024 H=16 Dh=64.  All matmuls in bf16 MFMA (fp32 accum).
// R14: every 1-block/CU schedule stalls at ~68-72us (phase count irrelevant);
// the missing ingredient vs the old multi-block structure is INTER-BLOCK
// overlap.  gemm4: 8-phase/BK=64 schedule (R4-proven ordering + XOR swizzle
// + counted vmcnt) on a 128x128 tile, 4 waves, 64KB LDS -> 2 blocks/CU.
// Per-wave tile stays 64x64 (same LDS B/FLOP), stage 8 units/K-tile,
// vmcnt(8) at p4/p8.  QKV: 1536 blocks = 3.0 rounds @2/CU; Wo: 512 = 1.0.
// ---------------------------------------------------------------------------

typedef short  short8  __attribute__((ext_vector_type(8)));
typedef short  short4v __attribute__((ext_vector_type(4)));
typedef float  floatx4 __attribute__((ext_vector_type(4)));
typedef unsigned uint2v __attribute__((ext_vector_type(2)));

#define T_SZ 2048
#define DM   1024

// 0.125 (Dh^-0.5) * log2(e): softmax in base-2 domain -> native v_exp_f32
#define QSCALE 0.18033688011112042f

__device__ __forceinline__ short f2bf(float f) {
  unsigned u = __float_as_uint(f);
  u += 0x7fffu + ((u >> 16) & 1u);        // RNE
  return (short)(u >> 16);
}

#if defined(__has_builtin) && __has_builtin(__builtin_amdgcn_cvt_pk_bf16_f32)
typedef __bf16 bf16x2_t __attribute__((ext_vector_type(2)));
__device__ __forceinline__ unsigned pack_bf(float lo, float hi) {   // 1 VALU op
  return __builtin_bit_cast(unsigned, __builtin_amdgcn_cvt_pk_bf16_f32(lo, hi));
}
#else
__device__ __forceinline__ unsigned pack_bf(float lo, float hi) {   // 3 VALU ops
  return __builtin_amdgcn_perm(__float_as_uint(hi) + 0x8000u,
                               __float_as_uint(lo) + 0x8000u, 0x07060302u);
}
#endif

#if defined(__has_builtin) && __has_builtin(__builtin_amdgcn_exp2f)
__device__ __forceinline__ float fexp2(float x) { return __builtin_amdgcn_exp2f(x); }
#else
__device__ __forceinline__ float fexp2(float x) { return exp2f(x); }
#endif

__device__ __forceinline__ void gll16(const void* g, void* l) {
  __builtin_amdgcn_global_load_lds((const __attribute__((address_space(1))) void*)g,
                                   (__attribute__((address_space(3))) void*)l, 16, 0, 0);
}

#define SBAR() asm volatile("s_barrier" ::: "memory")
#define WLG()  asm volatile("s_waitcnt lgkmcnt(0)" ::: "memory")
#define WV8()  asm volatile("s_waitcnt vmcnt(8)" ::: "memory")
#define WV0()  asm volatile("s_waitcnt vmcnt(0)" ::: "memory")

// -------------------------------------------------- converts, one launch
// z in [0,4): W[z] fp32 [K,N] -> bf16 W^T [N,K]   (grid x,y = 32,32; block 32x8)
// z == 4   : x fp32 -> bf16 flat
__global__ void cvt_kernel(const float* __restrict__ s0, const float* __restrict__ s1,
                           const float* __restrict__ s2, const float* __restrict__ s3,
                           short* __restrict__ dst,
                           const float* __restrict__ x, short* __restrict__ xb) {
  const int tx = threadIdx.x, ty = threadIdx.y;       // block (32,8)
  if (blockIdx.z == 4) {                              // ---- x -> bf16
    const int tid = ty * 32 + tx;
    const int blk = blockIdx.y * 32 + blockIdx.x;     // 0..1023
    int i = (blk * 256 + tid) * 4;
#pragma unroll
    for (int j = 0; j < 8; ++j) {
      const float4 v = *(const float4*)(x + i);
      short4v o;
      o.x = f2bf(v.x); o.y = f2bf(v.y); o.z = f2bf(v.z); o.w = f2bf(v.w);
      *(short4v*)(xb + i) = o;
      i += 1048576;
    }
    return;
  }
  const float* srcs[4] = {s0, s1, s2, s3};
  const float* src = srcs[blockIdx.z];
  short* d = dst + (size_t)blockIdx.z * 1048576;
  __shared__ float tile[32][33];
  const int n_base = blockIdx.x * 32, k_base = blockIdx.y * 32;
#pragma unroll
  for (int j = 0; j < 4; ++j)
    tile[ty + j * 8][tx] = src[(size_t)(k_base + ty + j * 8) * 1024 + n_base + tx];
  __syncthreads();
#pragma unroll
  for (int j = 0; j < 4; ++j)
    d[(size_t)(n_base + ty + j * 8) * 1024 + k_base + tx] = f2bf(tile[tx][ty + j * 8]);
}

// -------------------------------------------------- transposed GEMM, 8-phase x 2 blocks/CU
// C^T = A[M,1024] * B[N,1024]^T, tile 128(m) x 128(n), BK=64, 256 thr
// (4 waves 2Mx2N, 64x64 each).  LDS 64 KB -> 2 blocks/CU (the inter-block
// overlap every 1-block/CU schedule lacked).  2-slot ring; per t-iter
// (2 K-tiles, 8 phases, R4-proven ordering):
//   p1: ds_read slot0 A-half0 (4) + all B (8) | MMQ(0,0)
//   p2: stage B0a(2)                          | MMQ(0,1)
//   p3: ds_read A-half1 (4), stage B0b(2)     | MMQ(1,0)
//   p4: stage A0 (4), vmcnt(8)                | MMQ(1,1)
//   p5-p8: mirror on slot1.
// Counted wait: steady-state 16 outstanding at p4/p8; drain to 8 = the slot
// read next phase has landed.  T2 swizzle: pre-swizzled global source
// (scol ^= srow&7) + matching XOR on ds_read col-block -> 0 conflicts.
// MODE 0: QKV epilogue (C^T: head-dim on quad/r -> packed short4v for Q/K;
//         V -> V^T 2B scatter).  grid 1536 = 3.0 rounds @ 2/CU.
// MODE 1: Wo epilogue fp32 float4.  grid 512 = 1.0 round @ 2/CU.
template <int MODE>
__global__ __launch_bounds__(256, 2) void gemm4(
    const short* __restrict__ A, const short* __restrict__ B,
    short* __restrict__ obf, short* __restrict__ vt, float* __restrict__ of) {
  __shared__ short As[2 * 128 * 64];   // [slot][128][64]  32 KB
  __shared__ short Bs[2 * 128 * 64];   // [slot][128][64]  32 KB
  const int tid  = threadIdx.x;
  const int w    = tid >> 6, lane = tid & 63;
  const int quad = lane >> 4, l15 = lane & 15;
  const int wr   = w >> 1, wc = w & 1;          // 2 (M) x 2 (N) waves
  const int fx   = l15 & 7;
  const int lid  = (int)blockIdx.x;
  // xcd = lid&7 owns a 1024-token B panel (2 MB, L2-local), walks m-tiles.
  const int xcd  = lid & 7, idx = lid >> 3;
  const int m0   = (idx >> 3) * 128;
  const int n0   = (xcd * 8 + (idx & 7)) * 128;
  const int srow = tid >> 3;                    // 0..31
  const int scol = ((tid & 7) ^ (srow & 7)) * 8;

  const short* Ag = A + (size_t)(m0 + srow) * 1024 + scol;
  const short* Bg = B + (size_t)(n0 + srow) * 1024 + scol;

  floatx4 acc[4][4] = {};
  short8 af[2][2], bf[4][2];

  // stage bursts: 2 gll16 each = 64 rows; A/B tiles = 128 rows = 2 bursts
#define SA0(slot, kb) do { \
    gll16(Ag + (kb),                        &As[(slot) * 8192 + tid * 8]); \
    gll16(Ag + (size_t)(32 * 1024) + (kb),  &As[(slot) * 8192 + 2048 + tid * 8]); \
  } while (0)
#define SA1(slot, kb) do { \
    gll16(Ag + (size_t)(64 * 1024) + (kb),  &As[(slot) * 8192 + 4096 + tid * 8]); \
    gll16(Ag + (size_t)(96 * 1024) + (kb),  &As[(slot) * 8192 + 6144 + tid * 8]); \
  } while (0)
#define SB0(slot, kb) do { \
    gll16(Bg + (kb),                        &Bs[(slot) * 8192 + tid * 8]); \
    gll16(Bg + (size_t)(32 * 1024) + (kb),  &Bs[(slot) * 8192 + 2048 + tid * 8]); \
  } while (0)
#define SB1(slot, kb) do { \
    gll16(Bg + (size_t)(64 * 1024) + (kb),  &Bs[(slot) * 8192 + 4096 + tid * 8]); \
    gll16(Bg + (size_t)(96 * 1024) + (kb),  &Bs[(slot) * 8192 + 6144 + tid * 8]); \
  } while (0)
#define LDA4(slot, ih) do { \
    _Pragma("unroll") for (int ii = 0; ii < 2; ++ii) \
    _Pragma("unroll") for (int s = 0; s < 2; ++s) \
      af[ii][s] = *(const short8*)&As[(slot) * 8192 + \
          (wr * 64 + (ih) * 32 + ii * 16 + l15) * 64 + ((s * 4 + quad) ^ fx) * 8]; \
  } while (0)
#define LDB8(slot) do { \
    _Pragma("unroll") for (int j = 0; j < 4; ++j) \
    _Pragma("unroll") for (int s = 0; s < 2; ++s) \
      bf[j][s] = *(const short8*)&Bs[(slot) * 8192 + \
          (wc * 64 + j * 16 + l15) * 64 + ((s * 4 + quad) ^ fx) * 8]; \
  } while (0)
#define MMQ(ih, jh) do { \
    __builtin_amdgcn_s_setprio(1); \
    _Pragma("unroll") for (int ii = 0; ii < 2; ++ii) \
    _Pragma("unroll") for (int jj = 0; jj < 2; ++jj) \
    _Pragma("unroll") for (int s = 0; s < 2; ++s) \
      acc[(ih) * 2 + ii][(jh) * 2 + jj] = __builtin_amdgcn_mfma_f32_16x16x32_bf16( \
          af[ii][s], bf[(jh) * 2 + jj][s], acc[(ih) * 2 + ii][(jh) * 2 + jj], 0, 0, 0); \
    __builtin_amdgcn_s_setprio(0); \
  } while (0)

  // prologue: kt0 -> slot0 (8), kt1 -> slot1 (8); WV8 -> slot0 landed.
  SB0(0, 0);  SB1(0, 0);  SA0(0, 0);  SA1(0, 0);
  SB0(1, 64); SB1(1, 64); SA0(1, 64); SA1(1, 64);
  WV8(); SBAR();

  for (int t = 0; t < 8; ++t) {
    const int kn2 = (2 * t + 2) * 64;          // -> slot0
    const int kn3 = (2 * t + 3) * 64;          // -> slot1
    const bool mre = (t < 7);
    // ---- p1
    LDA4(0, 0); LDB8(0);
    SBAR(); WLG(); MMQ(0, 0); SBAR();
    // ---- p2 (slot0-B fully read in p1, all waves past barrier)
    if (mre) SB0(0, kn2);
    MMQ(0, 1); SBAR();
    // ---- p3
    LDA4(0, 1);
    if (mre) SB1(0, kn2);
    SBAR(); WLG(); MMQ(1, 0); SBAR();
    // ---- p4: stage A0; wait: slot1 (oldest 8) landed for p5
    if (mre) { SA0(0, kn2); SA1(0, kn2); }
    MMQ(1, 1);
    if (mre) WV8(); else WV0();
    SBAR();
    // ---- p5
    LDA4(1, 0); LDB8(1);
    SBAR(); WLG(); MMQ(0, 0); SBAR();
    // ---- p6
    if (mre) SB0(1, kn3);
    MMQ(0, 1); SBAR();
    // ---- p7
    LDA4(1, 1);
    if (mre) SB1(1, kn3);
    SBAR(); WLG(); MMQ(1, 0); SBAR();
    // ---- p8: wait: next slot0 (oldest 8) landed
    if (mre) { SA0(1, kn3); SA1(1, kn3); }
    MMQ(1, 1);
    if (mre) WV8();
    SBAR();
  }

  // ---- epilogue: C^T[m = out col][n = token]
  if constexpr (MODE == 0) {
    const int wsel = m0 >> 10;                  // 0=Q 1=K 2=V, uniform/block
    const int nn0  = (m0 & 1023) + wr * 64;
    if (wsel < 2) {
      const float scale = (wsel == 0) ? QSCALE : 1.0f;
      short* outw = obf + (size_t)wsel * (64u * 2048u * 64u);
#pragma unroll
      for (int i = 0; i < 4; ++i) {
        const int nn = nn0 + i * 16 + quad * 4;  // qkv col, mult of 4
        const int h = nn >> 6, d = nn & 63;
#pragma unroll
        for (int j = 0; j < 4; ++j) {
          const int tg = n0 + wc * 64 + j * 16 + l15;
          const int b = tg >> 11, tt = tg & 2047;
          short4v o4;
#pragma unroll
          for (int r = 0; r < 4; ++r) o4[r] = f2bf(acc[i][j][r] * scale);
          *(short4v*)(outw + (((size_t)(b * 16 + h) * 2048 + tt) << 6) + d) = o4;
        }
      }
    } else {
#pragma unroll
      for (int i = 0; i < 4; ++i) {
        const int nn = nn0 + i * 16 + quad * 4;  // v col in [0,1024)
        const int h = nn >> 6, d = nn & 63;
#pragma unroll
        for (int j = 0; j < 4; ++j) {
          const int tg = n0 + wc * 64 + j * 16 + l15;
          const int b = tg >> 11, tt = tg & 2047;
#pragma unroll
          for (int r = 0; r < 4; ++r)
            vt[(((size_t)(b * 16 + h) * 64 + d + r) << 11) + tt] = f2bf(acc[i][j][r]);
        }
      }
    }
  } else {
    const int nn0 = m0 + wr * 64;
#pragma unroll
    for (int i = 0; i < 4; ++i) {
      const int nn = nn0 + i * 16 + quad * 4;    // out col, 16B aligned
#pragma unroll
      for (int j = 0; j < 4; ++j) {
        const int tg = n0 + wc * 64 + j * 16 + l15;
        float4 o4;
        o4.x = acc[i][j][0]; o4.y = acc[i][j][1];
        o4.z = acc[i][j][2]; o4.w = acc[i][j][3];
        *(float4*)(of + (size_t)tg * 1024 + nn) = o4;
      }
    }
  }
#undef SA0
#undef SA1
#undef SB0
#undef SB1
#undef LDA4
#undef LDB8
#undef MMQ
}

// -------------------------------------------------- flash attention (causal, transposed)
// grid (8, 64), block 512 (8 waves).  bh = bx + 8*(by&7) -> one XCD per bh
// group (K/V L2-local).  Block = one 256-row q-band (qb), waves 0..7 own
// 32 q rows each (strips A/B of 16; kf/vf frag reads feed both strips).
// All 8 waves share one staged K/V tile.  P chunk-interleaved (QK^T+PV per
// 32-col chunk), Ps = 2.5 KB/wave.  59.25 KB LDS -> 2 blocks/CU = 16
// waves/CU.  CU-pair balance: co-resident blocks get qb and 7-qb.
__global__ __launch_bounds__(512, 4) void attn_kernel(
    const short* __restrict__ Qg, const short* __restrict__ Kg,
    const short* __restrict__ Vt, short* __restrict__ ctx) {
  __shared__ short Ks[128 * 72];       // [t_k][d]                    18.00 KB
  __shared__ short Vs[80 * 136];       // [d][t_k], row 64 = ones     21.25 KB
  __shared__ short Ps[8 * 32 * 40];    // per-wave [q(32)][k(32)+pad] 20.00 KB

  const int tid  = threadIdx.x;
  const int w    = tid >> 6, lane = tid & 63;
  const int quad = lane >> 4, l15 = lane & 15;
  const int bh = (int)blockIdx.x + 8 * ((int)blockIdx.y & 7);
  const int g  = (int)blockIdx.y >> 3;
  const int qb = (g < 4) ? (7 - g) : (g - 4);   // CU pairs get qb + (7-qb)
  const int b  = bh >> 4, h = bh & 15;

  const size_t base = (size_t)bh * (T_SZ * 64);
  const short* Qb  = Qg + base;
  const short* Kb  = Kg + base;
  const short* Vtb = Vt + base;
  short* Pw = &Ps[w * 1280];

  // staging (512 thr): K row skr, 32B at col skp; V row svr, 32B at col svp
  const int skr = tid >> 2, skp = (tid & 3) * 16;
  const int svr = tid >> 3, svp = (tid & 7) * 16;

  // init Vs rows 64..79: row 64 = 1.0 (l-reduction), 65..79 = 0
  if (tid < 256) {
    const int rr = 64 + (tid >> 4), cb = (tid & 15) * 8;
    const short vv = (tid < 16) ? (short)0x3F80 : (short)0;
    short8 fill;
#pragma unroll
    for (int j = 0; j < 8; ++j) fill[j] = vv;
    *(short8*)&Vs[rr * 136 + cb] = fill;
  }

  const int rowA = qb * 256 + w * 32;          // strip A (16 q), strip B = +16
  const int rowB = rowA + 16;
  const int ktmax = 2 * qb + 2;

  const short8 qA0 = *(const short8*)(Qb + (size_t)(rowA + l15) * 64 + quad * 8);
  const short8 qA1 = *(const short8*)(Qb + (size_t)(rowA + l15) * 64 + 32 + quad * 8);
  const short8 qB0 = *(const short8*)(Qb + (size_t)(rowB + l15) * 64 + quad * 8);
  const short8 qB1 = *(const short8*)(Qb + (size_t)(rowB + l15) * 64 + 32 + quad * 8);

  floatx4 OA[4] = {}, OB[4] = {};
  floatx4 O5A = {}, O5B = {};                  // row: l in quad0/reg0

  // preload tile 0 into registers
  short8 kR[2], vR[2];
  kR[0] = *(const short8*)(Kb + (size_t)skr * 64 + skp);
  kR[1] = *(const short8*)(Kb + (size_t)skr * 64 + skp + 8);
  vR[0] = *(const short8*)(Vtb + (size_t)svr * 2048 + svp);
  vR[1] = *(const short8*)(Vtb + (size_t)svr * 2048 + svp + 8);

  for (int kt = 0; kt < ktmax; ++kt) {
    const int k0 = kt << 7;
    __syncthreads();                           // prior tile's LDS reads done
    *(short8*)&Ks[skr * 72 + skp]     = kR[0];
    *(short8*)&Ks[skr * 72 + skp + 8] = kR[1];
    *(short8*)&Vs[svr * 136 + svp]     = vR[0];
    *(short8*)&Vs[svr * 136 + svp + 8] = vR[1];
    if (kt + 1 < ktmax) {                      // prefetch next tile
      const int kn = (kt + 1) << 7;
      kR[0] = *(const short8*)(Kb + (size_t)(kn + skr) * 64 + skp);
      kR[1] = *(const short8*)(Kb + (size_t)(kn + skr) * 64 + skp + 8);
      vR[0] = *(const short8*)(Vtb + (size_t)svr * 2048 + kn + svp);
      vR[1] = *(const short8*)(Vtb + (size_t)svr * 2048 + kn + svp + 8);
    }
    __syncthreads();                           // staged LDS visible

    const int dkA = rowA - k0;                 // wave-uniform
    if (dkA < 0) continue;                     // tail: wave idle, barriers done
    const int dkB = dkA + 16;
    const int limA = dkA + l15, limB = limA + 16;
    const int naA = min(8, (dkA >> 4) + 1), nchA = (naA + 1) >> 1;
    const int naB = min(8, (dkB >> 4) + 1), nchB = (naB + 1) >> 1;

#pragma unroll
    for (int c = 0; c < 4; ++c) {
      if (c < nchB) {
        // ---- QK^T for the chunk's two 16-col tiles -> P LDS
#pragma unroll
        for (int mm = 0; mm < 2; ++mm) {
          const int mt = 2 * c + mm;
          const int pa = l15 * 40 + mm * 16 + quad * 4;          // strip A
          const int pb = (16 + l15) * 40 + mm * 16 + quad * 4;   // strip B
          const bool aB = (mt * 16 < dkB + 16);
          const bool aA = (mt * 16 < dkA + 16);
          if (aB) {
            const short8 kf0 = *(const short8*)&Ks[(mt * 16 + l15) * 72 + quad * 8];
            const short8 kf1 = *(const short8*)&Ks[(mt * 16 + l15) * 72 + 32 + quad * 8];
            {                                  // ---- strip B
              floatx4 s = {};
              s = __builtin_amdgcn_mfma_f32_16x16x32_bf16(kf0, qB0, s, 0, 0, 0);
              s = __builtin_amdgcn_mfma_f32_16x16x32_bf16(kf1, qB1, s, 0, 0, 0);
              if (mt * 16 + 15 > dkB) {
#pragma unroll
                for (int r = 0; r < 4; ++r)
                  if (mt * 16 + quad * 4 + r > limB) s[r] = -1e30f;
              }
              floatx4 e;
#pragma unroll
              for (int r = 0; r < 4; ++r) e[r] = fexp2(s[r]);
              uint2v pd;
              pd.x = pack_bf(e[0], e[1]);
              pd.y = pack_bf(e[2], e[3]);
              *(uint2v*)&Pw[pb] = pd;
            }
            if (c < nchA) {                    // ---- strip A (reuses kf)
              if (aA) {
                floatx4 s = {};
                s = __builtin_amdgcn_mfma_f32_16x16x32_bf16(kf0, qA0, s, 0, 0, 0);
                s = __builtin_amdgcn_mfma_f32_16x16x32_bf16(kf1, qA1, s, 0, 0, 0);
                if (mt * 16 + 15 > dkA) {
#pragma unroll
                  for (int r = 0; r < 4; ++r)
                    if (mt * 16 + quad * 4 + r > limA) s[r] = -1e30f;
                }
                floatx4 e;
#pragma unroll
                for (int r = 0; r < 4; ++r) e[r] = fexp2(s[r]);
                uint2v pd;
                pd.x = pack_bf(e[0], e[1]);
                pd.y = pack_bf(e[2], e[3]);
                *(uint2v*)&Pw[pa] = pd;
              } else {
                uint2v z; z.x = 0; z.y = 0;
                *(uint2v*)&Pw[pa] = z;
              }
            }
          } else {                             // aB false => aA false (mm==1)
            uint2v z; z.x = 0; z.y = 0;
            *(uint2v*)&Pw[pb] = z;
            if (c < nchA) *(uint2v*)&Pw[pa] = z;
          }
        }
        // ---- PV for chunk c
        const int vcol = c * 32 + quad * 8;
        const short8 vfl = *(const short8*)&Vs[(64 + l15) * 136 + vcol];
        short8 vf[4];
#pragma unroll
        for (int dt = 0; dt < 4; ++dt)
          vf[dt] = *(const short8*)&Vs[(dt * 16 + l15) * 136 + vcol];
        const short8 pfB = *(const short8*)&Pw[(16 + l15) * 40 + quad * 8];
#pragma unroll
        for (int dt = 0; dt < 4; ++dt)
          OB[dt] = __builtin_amdgcn_mfma_f32_16x16x32_bf16(vf[dt], pfB, OB[dt], 0, 0, 0);
        O5B = __builtin_amdgcn_mfma_f32_16x16x32_bf16(vfl, pfB, O5B, 0, 0, 0);
        if (c < nchA) {                        // reuses vf/vfl
          const short8 pfA = *(const short8*)&Pw[l15 * 40 + quad * 8];
#pragma unroll
          for (int dt = 0; dt < 4; ++dt)
            OA[dt] = __builtin_amdgcn_mfma_f32_16x16x32_bf16(vf[dt], pfA, OA[dt], 0, 0, 0);
          O5A = __builtin_amdgcn_mfma_f32_16x16x32_bf16(vfl, pfA, O5A, 0, 0, 0);
        }
      }
    }
  }

  // epilogue: l = O5[0] of quad0 lane l15 (C-layout row 0 = ones-row d=64)
  {
    const float lA = __shfl(O5A[0], l15);
    const float invA = 1.0f / lA;
    const int t = rowA + l15;
    short* cb = ctx + (((size_t)(b * T_SZ + t)) << 10) + h * 64 + quad * 4;
#pragma unroll
    for (int dt = 0; dt < 4; ++dt) {
      short4v o4;
#pragma unroll
      for (int r = 0; r < 4; ++r) o4[r] = f2bf(OA[dt][r] * invA);
      *(short4v*)(cb + dt * 16) = o4;
    }
  }
  {
    const float lB = __shfl(O5B[0], l15);
    const float invB = 1.0f / lB;
    const int t = rowB + l15;
    short* cb = ctx + (((size_t)(b * T_SZ + t)) << 10) + h * 64 + quad * 4;
#pragma unroll
    for (int dt = 0; dt < 4; ++dt) {
      short4v o4;
#pragma unroll
      for (int r = 0; r < 4; ++r) o4[r] = f2bf(OB[dt][r] * invB);
      *(short4v*)(cb + dt * 16) = o4;
    }
  }
}

// --------------------------------------------------
extern "C" void kernel_launch(void* const* d_in, const int* in_sizes, int n_in,
                              void* d_out, int out_size, void* d_ws, size_t ws_size,
                              hipStream_t stream) {
  const float* x  = (const float*)d_in[0];
  const float* Wq = (const float*)d_in[1];
  const float* Wk = (const float*)d_in[2];
  const float* Wv = (const float*)d_in[3];
  const float* Wo = (const float*)d_in[4];
  float* out = (float*)d_out;

  // bf16 workspace (72 MB):
  //   xb [8M]  : x bf16; dead after gemm4<0> -> reused as ctx
  //   Wt [4x1M]: transposed weights
  //   Qb,Kb [8M each] : projections [bh][t][64]
  //   Vt [8M]  : V^T [bh][64][t]  (written directly by gemm4<0> epilogue)
  short* ws  = (short*)d_ws;
  short* xb  = ws;
  short* Wt  = ws + 8388608;
  short* Qb  = Wt + 4 * 1048576;
  short* Kb  = Qb + 8388608;
  short* Vt  = Kb + 8388608;
  short* ctx = xb;

  cvt_kernel<<<dim3(32, 32, 5), dim3(32, 8), 0, stream>>>(Wq, Wk, Wv, Wo, Wt, x, xb);
  gemm4<0><<<dim3(1536), 256, 0, stream>>>(Wt, xb, Qb, Vt, nullptr);
  attn_kernel<<<dim3(8, 64), 512, 0, stream>>>(Qb, Kb, Vt, ctx);
  gemm4<1><<<dim3(512), 256, 0, stream>>>(Wt + 3 * 1048576, ctx, nullptr, nullptr, out);
}